// Round 5
// baseline (254.762 us; speedup 1.0000x reference)
//
#include <hip/hip_runtime.h>
#include <hip/hip_bf16.h>

typedef __bf16 bf16;
typedef __bf16 bf16x8 __attribute__((ext_vector_type(8)));
typedef __bf16 bf16x4 __attribute__((ext_vector_type(4)));
typedef float  f32x4  __attribute__((ext_vector_type(4)));

#define MFMA16(a,b,c) __builtin_amdgcn_mfma_f32_16x16x32_bf16(a, b, c, 0, 0, 0)

// async global->LDS, 16B per lane; lds dst is wave-uniform base + lane*16
__device__ __forceinline__ void gl2lds16(const bf16* g, bf16* l) {
    __builtin_amdgcn_global_load_lds(
        (__attribute__((address_space(1))) void*)g,
        (__attribute__((address_space(3))) void*)l, 16, 0, 0);
}

// ---------------------------------------------------------------------------
// fp32 -> bf16 bulk convert of q,k,v into one contiguous [12288][1024] buffer
// ---------------------------------------------------------------------------
__global__ __launch_bounds__(256)
void cvt_kernel(const float* __restrict__ s0, const float* __restrict__ s1,
                const float* __restrict__ s2, bf16* __restrict__ out)
{
    int gidx = blockIdx.x * 256 + threadIdx.x;        // vec8 group
    int t    = gidx >> 19;
    int off  = (gidx & 0x7FFFF) * 8;
    const float* src = (t == 0) ? s0 : (t == 1) ? s1 : s2;
    const float4 f0 = *(const float4*)&src[off];
    const float4 f1 = *(const float4*)&src[off + 4];
    bf16x8 p = { (bf16)f0.x, (bf16)f0.y, (bf16)f0.z, (bf16)f0.w,
                 (bf16)f1.x, (bf16)f1.y, (bf16)f1.z, (bf16)f1.w };
    *(bf16x8*)&out[(size_t)gidx * 8] = p;
}

// ---------------------------------------------------------------------------
// Fused Wq/Wk/Wv transpose: W[h][k][e] fp32 -> Wt[t*1Mi + (h*64+e)*1024 + k]
// grid (16, 1, 48): x = k-tile, z = t*16 + h
// ---------------------------------------------------------------------------
__global__ __launch_bounds__(256)
void wqkv_transpose(const float* __restrict__ Wq, const float* __restrict__ Wk,
                    const float* __restrict__ Wv, bf16* __restrict__ out)
{
    __shared__ bf16 Tl[64][72];
    const int t = blockIdx.z >> 4, h = blockIdx.z & 15;
    const float* inp = ((t == 0) ? Wq : (t == 1) ? Wk : Wv) + (size_t)h * 65536;
    bf16* outp = out + (size_t)t * 1024 * 1024 + (size_t)h * 65536;
    const int r0 = blockIdx.x * 64;
    const int tid = threadIdx.x;

    #pragma unroll
    for (int i = 0; i < 2; i++) {
        int s = tid + i * 256;
        int r = s >> 3, c8 = (s & 7) * 8;
        const float* ap = &inp[(size_t)(r0 + r) * 64 + c8];
        float4 f0 = *(const float4*)ap;
        float4 f1 = *(const float4*)(ap + 4);
        bf16x8 p = { (bf16)f0.x, (bf16)f0.y, (bf16)f0.z, (bf16)f0.w,
                     (bf16)f1.x, (bf16)f1.y, (bf16)f1.z, (bf16)f1.w };
        *(bf16x8*)&Tl[r][c8] = p;
    }
    __syncthreads();
    #pragma unroll
    for (int i = 0; i < 2; i++) {
        int s = tid + i * 256;
        int c = s >> 3, r8 = (s & 7) * 8;
        bf16x8 p;
        #pragma unroll
        for (int j = 0; j < 8; j++) p[j] = Tl[r8 + j][c];
        *(bf16x8*)&outp[(size_t)c * 1024 + r0 + r8] = p;
    }
}

// ---------------------------------------------------------------------------
// Wo[h][e][o] fp32 -> Wot[o][h*64+e].  grid (1, 16, 16)
// ---------------------------------------------------------------------------
__global__ __launch_bounds__(256)
void wo_transpose(const float* __restrict__ Wo, bf16* __restrict__ out)
{
    __shared__ bf16 Tl[64][72];
    const int h  = blockIdx.z;
    const int c0 = blockIdx.y * 64;
    const float* inp = Wo + (size_t)h * 65536;
    bf16* outp = out + (size_t)h * 64;
    const int tid = threadIdx.x;

    #pragma unroll
    for (int i = 0; i < 2; i++) {
        int s = tid + i * 256;
        int r = s >> 3, c8 = (s & 7) * 8;
        const float* ap = &inp[(size_t)r * 1024 + c0 + c8];
        float4 f0 = *(const float4*)ap;
        float4 f1 = *(const float4*)(ap + 4);
        bf16x8 p = { (bf16)f0.x, (bf16)f0.y, (bf16)f0.z, (bf16)f0.w,
                     (bf16)f1.x, (bf16)f1.y, (bf16)f1.z, (bf16)f1.w };
        *(bf16x8*)&Tl[r][c8] = p;
    }
    __syncthreads();
    #pragma unroll
    for (int i = 0; i < 2; i++) {
        int s = tid + i * 256;
        int c = s >> 3, r8 = (s & 7) * 8;
        bf16x8 p;
        #pragma unroll
        for (int j = 0; j < 8; j++) p[j] = Tl[r8 + j][c];
        *(bf16x8*)&outp[(size_t)(c0 + c) * 1024 + r8] = p;
    }
}

// ---------------------------------------------------------------------------
// Fused QKV projection GEMM: grid (96, 8); slab = blockIdx.x>>5 in {0,1,2}.
// slab 0 -> Qproj (scaled), slab 1 -> Kproj, slab 2 -> Vt (TRANSPOSED epilogue,
// written as bf16 into the d_out region, overwritten later by outproj).
// ---------------------------------------------------------------------------
__global__ __launch_bounds__(256)
void qkv_gemm(const bf16* __restrict__ Xcat, const bf16* __restrict__ Wqkv,
              bf16* __restrict__ Cq, bf16* __restrict__ Ck, bf16* __restrict__ Vt,
              float qscale)
{
    __shared__ bf16 Al[128 * 64];
    __shared__ bf16 Bl[128 * 64];
    const int slab  = blockIdx.x >> 5;
    const int mbase = (blockIdx.x & 31) * 128;
    const int nbase = blockIdx.y * 128;
    const int tid = threadIdx.x;
    const int w = tid >> 6, lane = tid & 63;
    const int lm = lane & 15, q4 = lane >> 4;
    const int wr = (w >> 1) * 64, wc = (w & 1) * 64;
    const int lrow = lane >> 3, lsw = ((lane & 7) ^ lrow) * 8;

    const bf16* A  = Xcat + (size_t)slab * 4096 * 1024;
    const bf16* Bt = Wqkv + (size_t)slab * 1024 * 1024;

    f32x4 acc[4][4] = {};

    for (int k0 = 0; k0 < 1024; k0 += 64) {
        __syncthreads();
        #pragma unroll
        for (int i = 0; i < 4; i++) {
            int c = w * 4 + i;
            gl2lds16(&A [(size_t)(mbase + c * 8 + lrow) * 1024 + k0 + lsw], &Al[c * 512]);
            gl2lds16(&Bt[(size_t)(nbase + c * 8 + lrow) * 1024 + k0 + lsw], &Bl[c * 512]);
        }
        __syncthreads();
        #pragma unroll
        for (int kk2 = 0; kk2 < 2; kk2++) {
            bf16x8 a[4], bfr[4];
            const int g = ((kk2 * 4 + q4) ^ (lm & 7)) * 8;
            #pragma unroll
            for (int i = 0; i < 4; i++) a[i]   = *(const bf16x8*)&Al[(wr + i * 16 + lm) * 64 + g];
            #pragma unroll
            for (int j = 0; j < 4; j++) bfr[j] = *(const bf16x8*)&Bl[(wc + j * 16 + lm) * 64 + g];
            #pragma unroll
            for (int i = 0; i < 4; i++)
                #pragma unroll
                for (int j = 0; j < 4; j++)
                    acc[i][j] = MFMA16(a[i], bfr[j], acc[i][j]);
        }
    }

    if (slab == 2) {
        // transposed epilogue: Vt[e][s], 8-byte stores of 4 consecutive s
        #pragma unroll
        for (int i = 0; i < 4; i++)
            #pragma unroll
            for (int j = 0; j < 4; j++) {
                int row = mbase + wr + i * 16 + q4 * 4;      // s
                int col = nbase + wc + j * 16 + lm;          // e
                bf16x4 p = { (bf16)acc[i][j][0], (bf16)acc[i][j][1],
                             (bf16)acc[i][j][2], (bf16)acc[i][j][3] };
                *(bf16x4*)&Vt[(size_t)col * 4096 + row] = p;
            }
    } else {
        bf16* C = (slab == 0) ? Cq : Ck;
        const float scale = (slab == 0) ? qscale : 1.0f;
        #pragma unroll
        for (int i = 0; i < 4; i++)
            #pragma unroll
            for (int j = 0; j < 4; j++)
                #pragma unroll
                for (int r = 0; r < 4; r++) {
                    int row = mbase + wr + i * 16 + q4 * 4 + r;
                    int col = nbase + wc + j * 16 + lm;
                    C[(size_t)row * 1024 + col] = (bf16)(acc[i][j][r] * scale);
                }
    }
}

// ---------------------------------------------------------------------------
// Output projection: out[4096,1024] fp32 = Hd bf16 @ Wot^T
// ---------------------------------------------------------------------------
__global__ __launch_bounds__(256)
void outproj_gemm(const bf16* __restrict__ A, const bf16* __restrict__ Bt,
                  float* __restrict__ C)
{
    __shared__ bf16 Al[128 * 64];
    __shared__ bf16 Bl[128 * 64];
    const int mbase = blockIdx.x * 128;
    const int nbase = blockIdx.y * 128;
    const int tid = threadIdx.x;
    const int w = tid >> 6, lane = tid & 63;
    const int lm = lane & 15, q4 = lane >> 4;
    const int wr = (w >> 1) * 64, wc = (w & 1) * 64;
    const int lrow = lane >> 3, lsw = ((lane & 7) ^ lrow) * 8;

    f32x4 acc[4][4] = {};

    for (int k0 = 0; k0 < 1024; k0 += 64) {
        __syncthreads();
        #pragma unroll
        for (int i = 0; i < 4; i++) {
            int c = w * 4 + i;
            gl2lds16(&A [(size_t)(mbase + c * 8 + lrow) * 1024 + k0 + lsw], &Al[c * 512]);
            gl2lds16(&Bt[(size_t)(nbase + c * 8 + lrow) * 1024 + k0 + lsw], &Bl[c * 512]);
        }
        __syncthreads();
        #pragma unroll
        for (int kk2 = 0; kk2 < 2; kk2++) {
            bf16x8 a[4], bfr[4];
            const int g = ((kk2 * 4 + q4) ^ (lm & 7)) * 8;
            #pragma unroll
            for (int i = 0; i < 4; i++) a[i]   = *(const bf16x8*)&Al[(wr + i * 16 + lm) * 64 + g];
            #pragma unroll
            for (int j = 0; j < 4; j++) bfr[j] = *(const bf16x8*)&Bl[(wc + j * 16 + lm) * 64 + g];
            #pragma unroll
            for (int i = 0; i < 4; i++)
                #pragma unroll
                for (int j = 0; j < 4; j++)
                    acc[i][j] = MFMA16(a[i], bfr[j], acc[i][j]);
        }
    }

    #pragma unroll
    for (int i = 0; i < 4; i++)
        #pragma unroll
        for (int j = 0; j < 4; j++)
            #pragma unroll
            for (int r = 0; r < 4; r++) {
                int row = mbase + wr + i * 16 + q4 * 4 + r;
                int col = nbase + wc + j * 16 + lm;
                C[(size_t)row * 1024 + col] = acc[i][j][r];
            }
}

// ---------------------------------------------------------------------------
// Flash attention, register-P design:
//   S^T = MFMA(A=K, B=Q)  ->  lane holds P for its own q (= lane&15)
//   P stays in registers as the A-operand of O = P*V with a permuted k-order;
//   V fragments use the SAME permutation (two b64 LDS reads each) -> exact.
// K-frags loaded direct from global (L1-resident); only V staged in LDS.
// kv-tile = 128, 16 barriers total. No running max (scores bounded in fp32).
// ---------------------------------------------------------------------------
__global__ __launch_bounds__(256)
void attn_kernel(const bf16* __restrict__ Qp, const bf16* __restrict__ Kp,
                 const bf16* __restrict__ Vt, bf16* __restrict__ Hd)
{
    __shared__ bf16 Vl[64 * 128];   // [e][kv swizzled], 16 KB

    const int qt = blockIdx.x, b = blockIdx.y, h = blockIdx.z;
    const int qbase = qt * 128;
    const int tid  = threadIdx.x;
    const int w    = tid >> 6, lane = tid & 63;
    const int lm   = lane & 15, q4 = lane >> 4;

    const bf16* Qh = Qp + (size_t)(b * 2048 + qbase + w * 32) * 1024 + h * 64;
    const bf16* Kh = Kp + (size_t)(b * 2048) * 1024 + h * 64;
    const bf16* Vh = Vt + (size_t)(h * 64) * 4096 + b * 2048;

    // Q fragments (loop-invariant): B-operand layout == A layout: q=lm, e=q4*8+j
    bf16x8 Qf[2][2];
    #pragma unroll
    for (int i = 0; i < 2; i++)
        #pragma unroll
        for (int kk2 = 0; kk2 < 2; kk2++)
            Qf[i][kk2] = *(const bf16x8*)&Qh[(size_t)(i * 16 + lm) * 1024 + kk2 * 32 + q4 * 8];

    f32x4 O[2][4] = {};
    float lsum[2] = {};

    // V staging params: lane -> row = c*4 + (lane>>4), phys group pg = lane&15,
    // data group dg = (pg&8) | ((pg^row)&7)  (low-3 XOR swizzle)
    const int vrow = lane >> 4;             // row offset within 4-row chunk
    const int vpg  = lane & 15;

    for (int kt = 0; kt < 16; kt++) {
        __syncthreads();
        #pragma unroll
        for (int i = 0; i < 4; i++) {
            int c   = w * 4 + i;            // chunk: rows c*4 .. c*4+3
            int row = c * 4 + vrow;
            int dg  = (vpg & 8) | ((vpg ^ row) & 7);
            gl2lds16(&Vh[(size_t)row * 4096 + kt * 128 + dg * 8], &Vl[c * 512]);
        }
        __syncthreads();

        #pragma unroll
        for (int kk4 = 0; kk4 < 4; kk4++) {     // kv 32-chunk within the tile
            // S^T for kv-chunk: A = K rows (direct global), B = Qf
            f32x4 St[2][2] = {{{}, {}}, {{}, {}}};
            #pragma unroll
            for (int ctp = 0; ctp < 2; ctp++) {
                int krow = kt * 128 + kk4 * 32 + ctp * 16 + lm;
                #pragma unroll
                for (int kk2 = 0; kk2 < 2; kk2++) {
                    bf16x8 kf = *(const bf16x8*)
                        &Kh[(size_t)krow * 1024 + kk2 * 32 + q4 * 8];
                    #pragma unroll
                    for (int i = 0; i < 2; i++)
                        St[i][ctp] = MFMA16(kf, Qf[i][kk2], St[i][ctp]);
                }
            }
            // P = exp2(S^T) packed into A-frag slots: slot j -> kv offset
            // (j>>2)*16 + q4*4 + (j&3)  (permuted k-order)
            bf16x8 Pf[2];
            #pragma unroll
            for (int i = 0; i < 2; i++)
                #pragma unroll
                for (int j = 0; j < 8; j++) {
                    float p = __builtin_amdgcn_exp2f(St[i][j >> 2][j & 3]);
                    lsum[i] += p;
                    Pf[i][j] = (bf16)p;
                }
            // O += P*V: V-frag slot (q4,j) -> same permuted kv order;
            // two b64 reads at kv = kk4*32 + q4*4 (+16)
            #pragma unroll
            for (int et = 0; et < 4; et++) {
                int row = et * 16 + lm;
                int dg1 = kk4 * 4 + (q4 >> 1);
                int dg2 = dg1 + 2;
                int pg1 = (dg1 & 8) | ((dg1 ^ row) & 7);
                int pg2 = (dg2 & 8) | ((dg2 ^ row) & 7);
                bf16x4 v0 = *(const bf16x4*)&Vl[row * 128 + pg1 * 8 + (q4 & 1) * 4];
                bf16x4 v1 = *(const bf16x4*)&Vl[row * 128 + pg2 * 8 + (q4 & 1) * 4];
                bf16x8 vf = { v0[0], v0[1], v0[2], v0[3],
                              v1[0], v1[1], v1[2], v1[3] };
                #pragma unroll
                for (int i = 0; i < 2; i++)
                    O[i][et] = MFMA16(Pf[i], vf, O[i][et]);
            }
        }
    }

    // normalization: lane's lsum is partial (its q4's kv share) for q = ..+lm.
    // reduce across q4 (xor 16,32), then redistribute to O's row-q (q4*4+r).
    float rl[2][4];
    #pragma unroll
    for (int i = 0; i < 2; i++) {
        float l = lsum[i];
        l += __shfl_xor(l, 16, 64);
        l += __shfl_xor(l, 32, 64);
        #pragma unroll
        for (int r = 0; r < 4; r++) {
            float lr = __shfl(l, (lane & 48) + ((lane >> 4) & 3) * 4 + r, 64);
            rl[i][r] = 1.0f / lr;
        }
    }

    #pragma unroll
    for (int i = 0; i < 2; i++)
        #pragma unroll
        for (int et = 0; et < 4; et++)
            #pragma unroll
            for (int r = 0; r < 4; r++) {
                int row = b * 2048 + qbase + w * 32 + i * 16 + q4 * 4 + r;
                Hd[(size_t)row * 1024 + h * 64 + et * 16 + lm] =
                    (bf16)(O[i][et][r] * rl[i][r]);
            }
}

extern "C" void kernel_launch(void* const* d_in, const int* in_sizes, int n_in,
                              void* d_out, int out_size, void* d_ws, size_t ws_size,
                              hipStream_t stream)
{
    const float* q  = (const float*)d_in[0];
    const float* k  = (const float*)d_in[1];
    const float* v  = (const float*)d_in[2];
    const float* Wq = (const float*)d_in[3];
    const float* Wk = (const float*)d_in[4];
    const float* Wv = (const float*)d_in[5];
    const float* Wo = (const float*)d_in[6];
    float* out = (float*)d_out;

    // ws (bf16 elems, Mi = 1024*1024; 24Mi = 48 MB):
    //  [ 0, 4) qb   -> Hd (attn output; qb dead after qkv_gemm)
    //  [ 4, 8) kb
    //  [ 8,12) vb
    //  [12,15) Wqkv   [15,16) Wot   [16,20) Qproj   [20,24) Kproj
    // Vt (bf16, 8 MB) lives in the d_out region (16 MB fp32), overwritten
    // by outproj at the very end.
    const size_t Mi = 1024 * 1024;
    bf16* Xcat  = (bf16*)d_ws;
    bf16* Hd    = Xcat;                   // alias qb
    bf16* Wqkv  = Xcat + 12 * Mi;
    bf16* Wot   = Xcat + 15 * Mi;
    bf16* Qproj = Xcat + 16 * Mi;
    bf16* Kproj = Xcat + 20 * Mi;
    bf16* Vtb   = (bf16*)d_out;

    const float qscale = 0.125f * 1.4426950408889634f;  // 1/sqrt(64) * log2(e)

    cvt_kernel<<<6144, 256, 0, stream>>>(q, k, v, Xcat);
    wqkv_transpose<<<dim3(16, 1, 48), 256, 0, stream>>>(Wq, Wk, Wv, Wqkv);
    wo_transpose<<<dim3(1, 16, 16), 256, 0, stream>>>(Wo, Wot);

    qkv_gemm<<<dim3(96, 8), 256, 0, stream>>>(Xcat, Wqkv, Qproj, Kproj, Vtb, qscale);

    attn_kernel<<<dim3(16, 2, 16), 256, 0, stream>>>(Qproj, Kproj, Vtb, Hd);

    outproj_gemm<<<dim3(32, 8), 256, 0, stream>>>(Hd, Wot, out);
}

// Round 6
// 216.027 us; speedup vs baseline: 1.1793x; 1.1793x over previous
//
#include <hip/hip_runtime.h>
#include <hip/hip_bf16.h>

typedef __bf16 bf16;
typedef __bf16 bf16x8 __attribute__((ext_vector_type(8)));
typedef __bf16 bf16x4 __attribute__((ext_vector_type(4)));
typedef float  f32x4  __attribute__((ext_vector_type(4)));

#define MFMA16(a,b,c) __builtin_amdgcn_mfma_f32_16x16x32_bf16(a, b, c, 0, 0, 0)

// async global->LDS, 16B per lane; lds dst is wave-uniform base + lane*16
__device__ __forceinline__ void gl2lds16(const bf16* g, bf16* l) {
    __builtin_amdgcn_global_load_lds(
        (__attribute__((address_space(1))) void*)g,
        (__attribute__((address_space(3))) void*)l, 16, 0, 0);
}

// ---------------------------------------------------------------------------
// Fused prep: blocks [0,6144) fp32->bf16 cvt of q|k|v; [6144,6912) Wq/Wk/Wv
// transpose; [6912,7168) Wo transpose.
// ---------------------------------------------------------------------------
__global__ __launch_bounds__(256)
void prep_kernel(const float* __restrict__ q, const float* __restrict__ k,
                 const float* __restrict__ v, const float* __restrict__ Wq,
                 const float* __restrict__ Wk, const float* __restrict__ Wv,
                 const float* __restrict__ Wo, bf16* __restrict__ Xcat,
                 bf16* __restrict__ Wqkv, bf16* __restrict__ Wot)
{
    __shared__ bf16 Tl[64][72];
    const int bid = blockIdx.x;
    const int tid = threadIdx.x;

    if (bid < 6144) {
        int gidx = bid * 256 + tid;                   // vec8 group
        int t    = gidx >> 19;
        int off  = (gidx & 0x7FFFF) * 8;
        const float* src = (t == 0) ? q : (t == 1) ? k : v;
        const float4 f0 = *(const float4*)&src[off];
        const float4 f1 = *(const float4*)&src[off + 4];
        bf16x8 p = { (bf16)f0.x, (bf16)f0.y, (bf16)f0.z, (bf16)f0.w,
                     (bf16)f1.x, (bf16)f1.y, (bf16)f1.z, (bf16)f1.w };
        *(bf16x8*)&Xcat[(size_t)gidx * 8] = p;
        return;
    }
    if (bid < 6912) {
        // W[h][k][e] fp32 -> Wqkv[t*1Mi + (h*64+e)*1024 + k]
        int idx = bid - 6144;                         // 768
        int x = idx & 15, z = idx >> 4;               // x: k-tile, z = t*16+h
        int t = z >> 4, h = z & 15;
        const float* inp = ((t == 0) ? Wq : (t == 1) ? Wk : Wv) + (size_t)h * 65536;
        bf16* outp = Wqkv + (size_t)t * 1024 * 1024 + (size_t)h * 65536;
        int r0 = x * 64;
        #pragma unroll
        for (int i = 0; i < 2; i++) {
            int s = tid + i * 256;
            int r = s >> 3, c8 = (s & 7) * 8;
            const float* ap = &inp[(size_t)(r0 + r) * 64 + c8];
            float4 f0 = *(const float4*)ap;
            float4 f1 = *(const float4*)(ap + 4);
            bf16x8 p = { (bf16)f0.x, (bf16)f0.y, (bf16)f0.z, (bf16)f0.w,
                         (bf16)f1.x, (bf16)f1.y, (bf16)f1.z, (bf16)f1.w };
            *(bf16x8*)&Tl[r][c8] = p;
        }
        __syncthreads();
        #pragma unroll
        for (int i = 0; i < 2; i++) {
            int s = tid + i * 256;
            int c = s >> 3, r8 = (s & 7) * 8;
            bf16x8 p;
            #pragma unroll
            for (int j = 0; j < 8; j++) p[j] = Tl[r8 + j][c];
            *(bf16x8*)&outp[(size_t)c * 1024 + r0 + r8] = p;
        }
        return;
    }
    // Wo[h][e][o] fp32 -> Wot[o][h*64+e]
    {
        int idx = bid - 6912;                         // 256
        int y = idx & 15, h = idx >> 4;
        int c0 = y * 64;
        const float* inp = Wo + (size_t)h * 65536;
        bf16* outp = Wot + (size_t)h * 64;
        #pragma unroll
        for (int i = 0; i < 2; i++) {
            int s = tid + i * 256;
            int r = s >> 3, c8 = (s & 7) * 8;
            const float* ap = &inp[(size_t)r * 1024 + c0 + c8];
            float4 f0 = *(const float4*)ap;
            float4 f1 = *(const float4*)(ap + 4);
            bf16x8 p = { (bf16)f0.x, (bf16)f0.y, (bf16)f0.z, (bf16)f0.w,
                         (bf16)f1.x, (bf16)f1.y, (bf16)f1.z, (bf16)f1.w };
            *(bf16x8*)&Tl[r][c8] = p;
        }
        __syncthreads();
        #pragma unroll
        for (int i = 0; i < 2; i++) {
            int s = tid + i * 256;
            int c = s >> 3, r8 = (s & 7) * 8;
            bf16x8 p;
            #pragma unroll
            for (int j = 0; j < 8; j++) p[j] = Tl[r8 + j][c];
            *(bf16x8*)&outp[(size_t)(c0 + c) * 1024 + r8] = p;
        }
    }
}

// ---------------------------------------------------------------------------
// Fused QKV projection GEMM: grid (96, 8); slab = blockIdx.x>>5 in {0,1,2}.
// slab 0 -> Qproj (scaled), slab 1 -> Kproj, slab 2 -> Vt transposed epilogue
// with the 32-block kv PERMUTATION: pos(s) = (s&~31) | ((s>>2)&3)*8 |
// ((s>>4)&1)*4 | (s&3), so attn V-fragments are contiguous b128 reads.
// ---------------------------------------------------------------------------
__global__ __launch_bounds__(256)
void qkv_gemm(const bf16* __restrict__ Xcat, const bf16* __restrict__ Wqkv,
              bf16* __restrict__ Cq, bf16* __restrict__ Ck, bf16* __restrict__ Vt,
              float qscale)
{
    __shared__ bf16 Al[128 * 64];
    __shared__ bf16 Bl[128 * 64];
    const int slab  = blockIdx.x >> 5;
    const int mbase = (blockIdx.x & 31) * 128;
    const int nbase = blockIdx.y * 128;
    const int tid = threadIdx.x;
    const int w = tid >> 6, lane = tid & 63;
    const int lm = lane & 15, q4 = lane >> 4;
    const int wr = (w >> 1) * 64, wc = (w & 1) * 64;
    const int lrow = lane >> 3, lsw = ((lane & 7) ^ lrow) * 8;

    const bf16* A  = Xcat + (size_t)slab * 4096 * 1024;
    const bf16* Bt = Wqkv + (size_t)slab * 1024 * 1024;

    f32x4 acc[4][4] = {};

    for (int k0 = 0; k0 < 1024; k0 += 64) {
        __syncthreads();
        #pragma unroll
        for (int i = 0; i < 4; i++) {
            int c = w * 4 + i;
            gl2lds16(&A [(size_t)(mbase + c * 8 + lrow) * 1024 + k0 + lsw], &Al[c * 512]);
            gl2lds16(&Bt[(size_t)(nbase + c * 8 + lrow) * 1024 + k0 + lsw], &Bl[c * 512]);
        }
        __syncthreads();
        #pragma unroll
        for (int kk2 = 0; kk2 < 2; kk2++) {
            bf16x8 a[4], bfr[4];
            const int g = ((kk2 * 4 + q4) ^ (lm & 7)) * 8;
            #pragma unroll
            for (int i = 0; i < 4; i++) a[i]   = *(const bf16x8*)&Al[(wr + i * 16 + lm) * 64 + g];
            #pragma unroll
            for (int j = 0; j < 4; j++) bfr[j] = *(const bf16x8*)&Bl[(wc + j * 16 + lm) * 64 + g];
            #pragma unroll
            for (int i = 0; i < 4; i++)
                #pragma unroll
                for (int j = 0; j < 4; j++)
                    acc[i][j] = MFMA16(a[i], bfr[j], acc[i][j]);
        }
    }

    if (slab == 2) {
        #pragma unroll
        for (int i = 0; i < 4; i++)
            #pragma unroll
            for (int j = 0; j < 4; j++) {
                int s0  = mbase + wr + i * 16 + q4 * 4;      // kv, multiple of 4
                int col = nbase + wc + j * 16 + lm;          // e
                int sp  = (s0 & ~31) | (((s0 >> 2) & 3) * 8) | (((s0 >> 4) & 1) * 4);
                bf16x4 p = { (bf16)acc[i][j][0], (bf16)acc[i][j][1],
                             (bf16)acc[i][j][2], (bf16)acc[i][j][3] };
                *(bf16x4*)&Vt[(size_t)col * 4096 + sp] = p;
            }
    } else {
        bf16* C = (slab == 0) ? Cq : Ck;
        const float scale = (slab == 0) ? qscale : 1.0f;
        #pragma unroll
        for (int i = 0; i < 4; i++)
            #pragma unroll
            for (int j = 0; j < 4; j++)
                #pragma unroll
                for (int r = 0; r < 4; r++) {
                    int row = mbase + wr + i * 16 + q4 * 4 + r;
                    int col = nbase + wc + j * 16 + lm;
                    C[(size_t)row * 1024 + col] = (bf16)(acc[i][j][r] * scale);
                }
    }
}

// ---------------------------------------------------------------------------
// Output projection, 64x128 (MxN) tiles, grid (64, 8) = 2 blocks/CU.
// out[4096,1024] fp32 = Hd bf16 @ Wot^T
// ---------------------------------------------------------------------------
__global__ __launch_bounds__(256)
void outproj_gemm(const bf16* __restrict__ A, const bf16* __restrict__ Bt,
                  float* __restrict__ C)
{
    __shared__ bf16 Al[64 * 64];
    __shared__ bf16 Bl[128 * 64];
    const int mbase = blockIdx.x * 64;
    const int nbase = blockIdx.y * 128;
    const int tid = threadIdx.x;
    const int w = tid >> 6, lane = tid & 63;
    const int lm = lane & 15, q4 = lane >> 4;
    const int wm = (w >> 1) * 32, wn = (w & 1) * 64;   // 32x64 per wave
    const int lrow = lane >> 3, lsw = ((lane & 7) ^ lrow) * 8;

    f32x4 acc[2][4] = {};

    for (int k0 = 0; k0 < 1024; k0 += 64) {
        __syncthreads();
        #pragma unroll
        for (int i = 0; i < 2; i++) {
            int c = w * 2 + i;                          // 8 chunks of 8 rows
            gl2lds16(&A[(size_t)(mbase + c * 8 + lrow) * 1024 + k0 + lsw], &Al[c * 512]);
        }
        #pragma unroll
        for (int i = 0; i < 4; i++) {
            int c = w * 4 + i;                          // 16 chunks of 8 rows
            gl2lds16(&Bt[(size_t)(nbase + c * 8 + lrow) * 1024 + k0 + lsw], &Bl[c * 512]);
        }
        __syncthreads();
        #pragma unroll
        for (int kk2 = 0; kk2 < 2; kk2++) {
            bf16x8 a[2], bfr[4];
            const int g = ((kk2 * 4 + q4) ^ (lm & 7)) * 8;
            #pragma unroll
            for (int i = 0; i < 2; i++) a[i]   = *(const bf16x8*)&Al[(wm + i * 16 + lm) * 64 + g];
            #pragma unroll
            for (int j = 0; j < 4; j++) bfr[j] = *(const bf16x8*)&Bl[(wn + j * 16 + lm) * 64 + g];
            #pragma unroll
            for (int i = 0; i < 2; i++)
                #pragma unroll
                for (int j = 0; j < 4; j++)
                    acc[i][j] = MFMA16(a[i], bfr[j], acc[i][j]);
        }
    }

    #pragma unroll
    for (int i = 0; i < 2; i++)
        #pragma unroll
        for (int j = 0; j < 4; j++)
            #pragma unroll
            for (int r = 0; r < 4; r++) {
                int row = mbase + wm + i * 16 + q4 * 4 + r;
                int col = nbase + wn + j * 16 + lm;
                C[(size_t)row * 1024 + col] = acc[i][j][r];
            }
}

// ---------------------------------------------------------------------------
// Flash attention, register-P + staged K + permuted V + double buffer.
//   S^T = MFMA(A=K_lds, B=Q_regs)   -> lane holds P for q = lane&15
//   P packed in regs as the PV A-operand (permuted k-order);
//   V pre-permuted in global so V-frags are contiguous b128 LDS reads.
// One barrier per kv-64 tile; next tile's global_load_lds issued before
// compute so loads overlap MFMA.
// ---------------------------------------------------------------------------
__global__ __launch_bounds__(256)
void attn_kernel(const bf16* __restrict__ Qp, const bf16* __restrict__ Kp,
                 const bf16* __restrict__ Vt, bf16* __restrict__ Hd)
{
    __shared__ bf16 Kl[2][64 * 64];
    __shared__ bf16 Vl[2][64 * 64];

    const int qt = blockIdx.x, b = blockIdx.y, h = blockIdx.z;
    const int qbase = qt * 128;
    const int tid  = threadIdx.x;
    const int w    = tid >> 6, lane = tid & 63;
    const int lm   = lane & 15, q4 = lane >> 4;
    const int lrow = lane >> 3, lsw = ((lane & 7) ^ lrow) * 8;

    const bf16* Qh = Qp + (size_t)(b * 2048 + qbase + w * 32) * 1024 + h * 64;
    const bf16* Kh = Kp + (size_t)(b * 2048) * 1024 + h * 64;
    const bf16* Vh = Vt + (size_t)(h * 64) * 4096 + b * 2048;

    // Q fragments (loop-invariant), B-operand layout: n=lm, k=q4*8+j
    bf16x8 Qf[2][2];
    #pragma unroll
    for (int i = 0; i < 2; i++)
        #pragma unroll
        for (int kk2 = 0; kk2 < 2; kk2++)
            Qf[i][kk2] = *(const bf16x8*)&Qh[(size_t)(i * 16 + lm) * 1024 + kk2 * 32 + q4 * 8];

    f32x4 O[2][4] = {};
    float lsum[2] = {};

    // stage kv-tile kt into buffer d (K rows=kv, V rows=e; identical pattern)
    auto stage = [&](int kt, int d) {
        #pragma unroll
        for (int i = 0; i < 2; i++) {
            int c = w * 2 + i;                           // 8 chunks of 8 rows
            gl2lds16(&Kh[(size_t)(kt * 64 + c * 8 + lrow) * 1024 + lsw], &Kl[d][c * 512]);
            gl2lds16(&Vh[(size_t)(c * 8 + lrow) * 4096 + kt * 64 + lsw], &Vl[d][c * 512]);
        }
    };

    stage(0, 0);

    for (int kt = 0; kt < 32; kt++) {
        __syncthreads();                                 // buf[kt&1] ready
        if (kt < 31) stage(kt + 1, (kt + 1) & 1);        // overlap with compute
        const bf16* Kd = &Kl[kt & 1][0];
        const bf16* Vd = &Vl[kt & 1][0];

        // S^T: rows = kv (4 ctp tiles of 16), cols = q (2 strips)
        f32x4 St[2][4] = {};
        #pragma unroll
        for (int ctp = 0; ctp < 4; ctp++) {
            #pragma unroll
            for (int kk2 = 0; kk2 < 2; kk2++) {
                const int g = ((kk2 * 4 + q4) ^ (lm & 7)) * 8;
                bf16x8 kf = *(const bf16x8*)&Kd[(ctp * 16 + lm) * 64 + g];
                #pragma unroll
                for (int i = 0; i < 2; i++)
                    St[i][ctp] = MFMA16(kf, Qf[i][kk2], St[i][ctp]);
            }
        }

        // per kv-32 chunk: P = exp2(S^T) packed into A-slots; O += P*V
        #pragma unroll
        for (int kk4 = 0; kk4 < 2; kk4++) {
            bf16x8 Pf[2];
            #pragma unroll
            for (int i = 0; i < 2; i++)
                #pragma unroll
                for (int j = 0; j < 8; j++) {
                    float p = __builtin_amdgcn_exp2f(St[i][kk4 * 2 + (j >> 2)][j & 3]);
                    lsum[i] += p;
                    Pf[i][j] = (bf16)p;
                }
            #pragma unroll
            for (int et = 0; et < 4; et++) {
                const int g = ((kk4 * 4 + q4) ^ (lm & 7)) * 8;
                bf16x8 vf = *(const bf16x8*)&Vd[(et * 16 + lm) * 64 + g];
                #pragma unroll
                for (int i = 0; i < 2; i++)
                    O[i][et] = MFMA16(Pf[i], vf, O[i][et]);
            }
        }
    }

    // lane's lsum covers its q4 kv-slice for q=lm: reduce across q4 (xor 16,32),
    // then redistribute to O's row-q (= q4*4+r) via shfl.
    float rl[2][4];
    #pragma unroll
    for (int i = 0; i < 2; i++) {
        float l = lsum[i];
        l += __shfl_xor(l, 16, 64);
        l += __shfl_xor(l, 32, 64);
        #pragma unroll
        for (int r = 0; r < 4; r++) {
            float lr = __shfl(l, (lane & 48) + ((lane >> 4) & 3) * 4 + r, 64);
            rl[i][r] = 1.0f / lr;
        }
    }

    #pragma unroll
    for (int i = 0; i < 2; i++)
        #pragma unroll
        for (int et = 0; et < 4; et++)
            #pragma unroll
            for (int r = 0; r < 4; r++) {
                int row = b * 2048 + qbase + w * 32 + i * 16 + q4 * 4 + r;
                Hd[(size_t)row * 1024 + h * 64 + et * 16 + lm] =
                    (bf16)(O[i][et][r] * rl[i][r]);
            }
}

extern "C" void kernel_launch(void* const* d_in, const int* in_sizes, int n_in,
                              void* d_out, int out_size, void* d_ws, size_t ws_size,
                              hipStream_t stream)
{
    const float* q  = (const float*)d_in[0];
    const float* k  = (const float*)d_in[1];
    const float* v  = (const float*)d_in[2];
    const float* Wq = (const float*)d_in[3];
    const float* Wk = (const float*)d_in[4];
    const float* Wv = (const float*)d_in[5];
    const float* Wo = (const float*)d_in[6];
    float* out = (float*)d_out;

    // ws (bf16 elems, Mi = 1024*1024; 24Mi = 48 MB):
    //  [ 0, 4) qb -> Hd (attn out; qb dead after qkv_gemm)   [ 4, 8) kb
    //  [ 8,12) vb    [12,15) Wqkv   [15,16) Wot   [16,20) Qproj   [20,24) Kproj
    // Vt (bf16, 8 MB, kv-permuted) lives in d_out (16 MB fp32), overwritten
    // by outproj at the very end.
    const size_t Mi = 1024 * 1024;
    bf16* Xcat  = (bf16*)d_ws;
    bf16* Hd    = Xcat;                   // alias qb
    bf16* Wqkv  = Xcat + 12 * Mi;
    bf16* Wot   = Xcat + 15 * Mi;
    bf16* Qproj = Xcat + 16 * Mi;
    bf16* Kproj = Xcat + 20 * Mi;
    bf16* Vtb   = (bf16*)d_out;

    const float qscale = 0.125f * 1.4426950408889634f;  // 1/sqrt(64) * log2(e)

    prep_kernel<<<7168, 256, 0, stream>>>(q, k, v, Wq, Wk, Wv, Wo, Xcat, Wqkv, Wot);
    qkv_gemm<<<dim3(96, 8), 256, 0, stream>>>(Xcat, Wqkv, Qproj, Kproj, Vtb, qscale);
    attn_kernel<<<dim3(16, 2, 16), 256, 0, stream>>>(Qproj, Kproj, Vtb, Hd);
    outproj_gemm<<<dim3(64, 8), 256, 0, stream>>>(Hd, Wot, out);
}